// Round 8
// baseline (280.079 us; speedup 1.0000x reference)
//
#include <hip/hip_runtime.h>

// Problem constants: B=16, C=256, H=96, W=96, REP_K=3
#define B_   16
#define C_   256
#define HH   96
#define WW   96
#define IMG  4     // batch images per block (pipelined)
#define TPB  64    // one wave per block

typedef _Float16 half8 __attribute__((ext_vector_type(8)));
typedef float   f32x16 __attribute__((ext_vector_type(16)));

// Circulant MFMA formulation (R4-R7-verified numerics & layouts):
//   out[h,w] = sum_j effw[(j-h) mod 96] * x[j,w] + (bias + pecorr[h])
//   pecorr[h] = sum_j effw[(j-h) mod 96] * pe[j]   (computed ONCE via MFMA)
// f16 two-term split (hh+lh+hl) -> ~fp32 accuracy.
//
// R3-R7 lesson: every stage->compute->store structure idles the memory
// system ~80% of each wave's lifetime (measured 4KB/CU outstanding).
// Fix: per-wave software pipeline over 4 images -- while MFMA'ing image i,
// image i+1's 48 coalesced loads (12 KB) are in flight, pinned by
// sched_barrier(0) so the compiler cannot sink them (R4 failure mode).
__global__ __launch_bounds__(TPB) void fused_circ_conv_mfma(
    const float* __restrict__ x,
    const float* __restrict__ meta_pe,
    const float* __restrict__ weight,
    const float* __restrict__ bias,
    const float* __restrict__ rep_weight,
    float* __restrict__ out)
{
    __shared__ float sW[2 * HH];            // 768 B: doubled effw (only LDS use)

    const int lane = threadIdx.x;           // 0..63
    const int blk  = blockIdx.x;            // s*1024 + c*4 + bg
    const int s    = blk >> 10;             // col-slice 0..2
    const int c    = (blk & 1023) >> 2;     // channel
    const int b0   = (blk & 3) * IMG;       // first batch image

    const int r32 = lane & 31;              // A-row / B-col within 32
    const int g   = lane >> 5;              // k-half 0/1

    // --- stage doubled effective weights (3 entries per lane) ---
#pragma unroll
    for (int t = 0; t < 3; ++t) {
        int u = lane + TPB * t;             // 0..191
        int k = (u < HH) ? u : u - HH;
        float w_ = weight[c * HH + k];
        if (k < 3) w_ += rep_weight[c * 3 + k];
        sW[u] = w_;
    }
    __syncthreads();

    // --- A fragments: 6 distinct (circulant; frag(m,kt)=frag(0,(kt-2m)%6)) ---
    // sW idx in [65,191]; 32 consecutive words per lane-group, 2-way over g -> free.
    half8 ah[6], al[6];
#pragma unroll
    for (int t = 0; t < 6; ++t) {
        const float* wp = sW + (96 + t * 16 + g * 8 - r32);
#pragma unroll
        for (int e = 0; e < 8; ++e) {
            float w_ = wp[e];
            _Float16 h = (_Float16)w_;
            ah[t][e] = h;
            al[t][e] = (_Float16)(w_ - (float)h);
        }
    }

    // --- acc0[m] = bias + pecorr, once per block via MFMA ---
    // B_pe[j][col] = pe[j] for all cols -> D[h][col] = pecorr[h] matches C-layout.
    const float bv = bias[c];
    f32x16 acc0[3];
    {
        half8 ph[6], pl[6];
        const float* pep = meta_pe + c * HH + g * 8;
#pragma unroll
        for (int kt = 0; kt < 6; ++kt) {
#pragma unroll
            for (int e = 0; e < 8; ++e) {
                float v = pep[kt * 16 + e];         // j = kt*16 + g*8 + e
                _Float16 h = (_Float16)v;
                ph[kt][e] = h;
                pl[kt][e] = (_Float16)(v - (float)h);
            }
        }
#pragma unroll
        for (int m = 0; m < 3; ++m) {
            f32x16 a;
#pragma unroll
            for (int i = 0; i < 16; ++i) a[i] = bv;
#pragma unroll
            for (int kt = 0; kt < 6; ++kt) {
                const int t = (kt + 6 - 2 * m) % 6;
                a = __builtin_amdgcn_mfma_f32_32x32x16_f16(ah[t], ph[kt], a, 0, 0, 0);
                a = __builtin_amdgcn_mfma_f32_32x32x16_f16(al[t], ph[kt], a, 0, 0, 0);
                a = __builtin_amdgcn_mfma_f32_32x32x16_f16(ah[t], pl[kt], a, 0, 0, 0);
            }
            acc0[m] = a;
        }
    }

    // --- per-lane global bases ---
    const int col = s * 32 + r32;
    const size_t IMGSTR = (size_t)C_ * HH * WW;              // floats between images
    const size_t base0  = (size_t)(b0 * C_ + c) * (HH * WW);
    const float* __restrict__ xl = x + base0 + (size_t)(g * 8) * WW + col;
    float* __restrict__ ol = out + base0 + col;

    // --- prologue: issue image 0 loads (48 coalesced dwords = 12 KB in flight) ---
    // per instr: lanes 0-31 = 128B row segment (g=0), lanes 32-63 = row+8 -> 2x128B.
    float bx[48];
#pragma unroll
    for (int kt = 0; kt < 6; ++kt)
#pragma unroll
        for (int e = 0; e < 8; ++e)
            bx[kt * 8 + e] = xl[(size_t)(kt * 16 + e) * WW];

#pragma unroll 1
    for (int img = 0; img < IMG; ++img) {
        // convert current image's staged values -> f16 split frags (waits loads)
        half8 bh[6], bl[6];
#pragma unroll
        for (int kt = 0; kt < 6; ++kt)
#pragma unroll
            for (int e = 0; e < 8; ++e) {
                float v = bx[kt * 8 + e];
                _Float16 h = (_Float16)v;
                bh[kt][e] = h;
                bl[kt][e] = (_Float16)(v - (float)h);
            }
        __builtin_amdgcn_sched_barrier(0);
        // issue NEXT image's loads now; they fly during MFMA+store below
        if (img + 1 < IMG) {
            const float* __restrict__ xn = xl + (size_t)(img + 1) * IMGSTR;
#pragma unroll
            for (int kt = 0; kt < 6; ++kt)
#pragma unroll
                for (int e = 0; e < 8; ++e)
                    bx[kt * 8 + e] = xn[(size_t)(kt * 16 + e) * WW];
        }
        __builtin_amdgcn_sched_barrier(0);

        // 3 m-tiles x 6 k-tiles x 3 split-terms = 54 MFMA, then store
        float* __restrict__ op = ol + (size_t)img * IMGSTR;
#pragma unroll
        for (int m = 0; m < 3; ++m) {
            f32x16 acc = acc0[m];
#pragma unroll
            for (int kt = 0; kt < 6; ++kt) {
                const int t = (kt + 6 - 2 * m) % 6;   // compile-time after unroll
                acc = __builtin_amdgcn_mfma_f32_32x32x16_f16(ah[t], bh[kt], acc, 0, 0, 0);
                acc = __builtin_amdgcn_mfma_f32_32x32x16_f16(al[t], bh[kt], acc, 0, 0, 0);
                acc = __builtin_amdgcn_mfma_f32_32x32x16_f16(ah[t], bl[kt], acc, 0, 0, 0);
            }
            // C/D layout (R4-verified): col = r32, row = (reg&3)+8*(reg>>2)+4*g
#pragma unroll
            for (int reg = 0; reg < 16; ++reg) {
                int row = m * 32 + (reg & 3) + 8 * (reg >> 2) + 4 * g;
                op[(size_t)row * WW] = acc[reg];      // bias+pecorr already in acc0
            }
        }
    }
}

extern "C" void kernel_launch(void* const* d_in, const int* in_sizes, int n_in,
                              void* d_out, int out_size, void* d_ws, size_t ws_size,
                              hipStream_t stream) {
    const float* x          = (const float*)d_in[0];
    const float* meta_pe    = (const float*)d_in[1];
    const float* weight     = (const float*)d_in[2];
    const float* bias       = (const float*)d_in[3];
    const float* rep_weight = (const float*)d_in[4];
    float* out = (float*)d_out;

    // grid: 3 slices x 256 channels x 4 batch-groups = 3072 one-wave blocks
    fused_circ_conv_mfma<<<dim3(3 * 1024), dim3(TPB), 0, stream>>>(
        x, meta_pe, weight, bias, rep_weight, out);
}